// Round 5
// baseline (427.101 us; speedup 1.0000x reference)
//
#include <hip/hip_runtime.h>
#include <hip/hip_cooperative_groups.h>

namespace cg = cooperative_groups;

#define NGRAPHS 64
#define DIM 480            // floats per row
#define NCH 224            // 128 scalar + 64 vec3 + 32 vec5 channels
#define EPS 1e-5f
#define TILE 128           // rows per (graph-aligned) tile
#define NCU 256            // MI355X CUs

typedef float f32x4 __attribute__((ext_vector_type(4)));

// ws layout (float slots):
// [0, 14336)        sumsq per (g, channel)        64*224
// [14336, 22528)    sum per (g, scalar channel)   64*128
// [22528, 22593)    start offsets (fallback path) 65 ints
// [22593, 22658)    tile prefix  (fallback path)  65 ints
#define OFF_SSQ   0
#define OFF_SUM   14336
#define OFF_START 22528
#define OFF_TPRE  22593
#define ZN_FLOATS 22528

__device__ __forceinline__ int col2ch(int col) {
    if (col < 128) return col;
    if (col < 320) return 128 + (col - 128) / 3;
    return 192 + (col - 320) / 5;
}

__device__ __forceinline__ void flush_quad(float* __restrict__ SQ, int col0,
                                           float v0, float v1, float v2, float v3) {
    float v[4] = {v0, v1, v2, v3};
    int ch0 = col2ch(col0), ch1 = col2ch(col0 + 1),
        ch2 = col2ch(col0 + 2), ch3 = col2ch(col0 + 3);
    float acc = v[0]; int cur = ch0;
    if (ch1 == cur) acc += v[1]; else { atomicAdd(&SQ[cur], acc); cur = ch1; acc = v[1]; }
    if (ch2 == cur) acc += v[2]; else { atomicAdd(&SQ[cur], acc); cur = ch2; acc = v[2]; }
    if (ch3 == cur) acc += v[3]; else { atomicAdd(&SQ[cur], acc); cur = ch3; acc = v[3]; }
    atomicAdd(&SQ[cur], acc);
}

// ---------- device helpers shared by both paths ----------

__device__ __forceinline__ void stats_tile(const float* __restrict__ x, int g,
                                           int r0, int r1, int tx, int ty, int t,
                                           float (*red)[13], float* __restrict__ ws) {
    float ssq[8]  = {0, 0, 0, 0, 0, 0, 0, 0};
    float ssum[4] = {0, 0, 0, 0};
    for (int r = r0 + ty; r < r1; r += 4) {
        const float4* rowp = (const float4*)(x + (size_t)r * DIM);
        float4 v0 = rowp[tx];
        ssq[0] += v0.x * v0.x; ssq[1] += v0.y * v0.y;
        ssq[2] += v0.z * v0.z; ssq[3] += v0.w * v0.w;
        if (tx < 32) { ssum[0] += v0.x; ssum[1] += v0.y; ssum[2] += v0.z; ssum[3] += v0.w; }
        if (tx < 56) {
            float4 v1 = rowp[64 + tx];
            ssq[4] += v1.x * v1.x; ssq[5] += v1.y * v1.y;
            ssq[6] += v1.z * v1.z; ssq[7] += v1.w * v1.w;
        }
    }
#pragma unroll
    for (int j = 0; j < 8; ++j) red[t][j] = ssq[j];
#pragma unroll
    for (int j = 0; j < 4; ++j) red[t][8 + j] = ssum[j];
    __syncthreads();
    if (ty == 0) {
        float s[8], sm[4];
#pragma unroll
        for (int j = 0; j < 8; ++j)
            s[j] = red[tx][j] + red[tx + 64][j] + red[tx + 128][j] + red[tx + 192][j];
#pragma unroll
        for (int j = 0; j < 4; ++j)
            sm[j] = red[tx][8 + j] + red[tx + 64][8 + j] + red[tx + 128][8 + j] + red[tx + 192][8 + j];
        float* SQ = ws + OFF_SSQ + (size_t)g * NCH;
        float* SM = ws + OFF_SUM + (size_t)g * 128;
        flush_quad(SQ, 4 * tx, s[0], s[1], s[2], s[3]);
        if (tx < 32) {
#pragma unroll
            for (int j = 0; j < 4; ++j) atomicAdd(&SM[4 * tx + j], sm[j]);
        }
        if (tx < 56) flush_quad(SQ, 256 + 4 * tx, s[4], s[5], s[6], s[7]);
    }
    __syncthreads();
}

__device__ __forceinline__ void norm_tile(const float* __restrict__ x,
                                          const float* __restrict__ w,
                                          const float* __restrict__ bias,
                                          const float* __restrict__ ws,
                                          float* __restrict__ out,
                                          int g, int r0, int r1, int cnt_rows,
                                          int row_off, int c4) {
    float cnt = (float)max(cnt_rows, 1);
    const float* SQ = ws + OFF_SSQ + (size_t)g * NCH;
    const float* SM = ws + OFF_SUM + (size_t)g * 128;
    float A[4], B[4];
#pragma unroll
    for (int j = 0; j < 4; ++j) {
        int col = 4 * c4 + j;
        int ch = col2ch(col);
        float ssq = SQ[ch];
        if (col < 128) {
            float m   = SM[col] / cnt;
            float var = ssq / cnt - m * m;
            float Av  = rsqrtf(var + EPS) * w[ch];
            A[j] = Av;
            B[j] = bias[col] - m * Av;
        } else {
            float d = (col < 320) ? 3.0f : 5.0f;
            A[j] = rsqrtf(ssq / (d * cnt) + EPS) * w[ch];
            B[j] = 0.0f;
        }
    }
    const float4* xp = (const float4*)(x + (size_t)(r0 + row_off) * DIM) + c4;
    float*        op = out + (size_t)(r0 + row_off) * DIM + 4 * c4;
    const int stride4 = 2 * (DIM / 4);
    const int strideF = 2 * DIM;
    for (int r = r0 + row_off; r < r1; r += 2) {
        float4 xv = *xp;
        f32x4 o;
        o.x = xv.x * A[0] + B[0];
        o.y = xv.y * A[1] + B[1];
        o.z = xv.z * A[2] + B[2];
        o.w = xv.w * A[3] + B[3];
        __builtin_nontemporal_store(o, (f32x4*)op);
        xp += stride4;
        op += strideF;
    }
}

// ---------- primary path: single cooperative kernel ----------

__global__ __launch_bounds__(256, 4) void fused_kernel(
        const float* __restrict__ x, const int* __restrict__ bid,
        const float* __restrict__ w, const float* __restrict__ bias,
        float* __restrict__ ws, float* __restrict__ out, int N) {
    __shared__ int s_start[NGRAPHS + 1];
    __shared__ int s_tpre[NGRAPHS + 1];
    __shared__ float red[256][13];

    const int t  = threadIdx.x;
    const int tx = t & 63;
    const int ty = t >> 6;

    // phase 0: per-block graph offsets (LDS) + distributed zeroing
    if (t <= NGRAPHS) {
        int g = t, lo = 0, hi = N;
        while (lo < hi) { int mid = (lo + hi) >> 1; if (bid[mid] < g) lo = mid + 1; else hi = mid; }
        s_start[g] = lo;
    }
    for (int i = blockIdx.x * 256 + t; i < ZN_FLOATS; i += gridDim.x * 256)
        ws[i] = 0.0f;
    __syncthreads();
    if (t == 0) {
        int acc = 0;
        for (int g = 0; g < NGRAPHS; ++g) {
            s_tpre[g] = acc;
            acc += (s_start[g + 1] - s_start[g] + TILE - 1) / TILE;
        }
        s_tpre[NGRAPHS] = acc;
    }
    __syncthreads();
    const int ntiles = s_tpre[NGRAPHS];

    cg::this_grid().sync();                  // zeroing visible everywhere

    // phase 1: per-(graph,tile) sum / sumsq
    for (int b = blockIdx.x; b < ntiles; b += gridDim.x) {
        int lo = 0, hi = NGRAPHS;
        while (hi - lo > 1) { int mid = (lo + hi) >> 1; if (s_tpre[mid] <= b) lo = mid; else hi = mid; }
        int g  = lo;
        int r0 = s_start[g] + (b - s_tpre[g]) * TILE;
        int r1 = min(r0 + TILE, s_start[g + 1]);
        stats_tile(x, g, r0, r1, tx, ty, t, red, ws);
    }

    cg::this_grid().sync();                  // stats complete everywhere

    // phase 2: out = x*A + B, reversed tile order (L3-warm tail first)
    const int row_off = t / 120;
    const int c4 = t - row_off * 120;
    for (int k = blockIdx.x; k < ntiles; k += gridDim.x) {
        int b = ntiles - 1 - k;
        if (t < 240) {
            int lo = 0, hi = NGRAPHS;
            while (hi - lo > 1) { int mid = (lo + hi) >> 1; if (s_tpre[mid] <= b) lo = mid; else hi = mid; }
            int g  = lo;
            int r0 = s_start[g] + (b - s_tpre[g]) * TILE;
            int r1 = min(r0 + TILE, s_start[g + 1]);
            norm_tile(x, w, bias, ws, out, g, r0, r1,
                      s_start[g + 1] - s_start[g], row_off, c4);
        }
    }
}

// ---------- fallback path: round-3 three-kernel sequence ----------

__global__ __launch_bounds__(256) void init_kernel(const int* __restrict__ bid,
                                                   float* __restrict__ ws, int N) {
    int b = blockIdx.x;
    if (b < 88) {
        int i = b * 256 + threadIdx.x;
        if (i < ZN_FLOATS) ws[i] = 0.0f;
        return;
    }
    int* start = (int*)(ws + OFF_START);
    int* tpre  = (int*)(ws + OFF_TPRE);
    int g = threadIdx.x;
    if (g <= NGRAPHS) {
        int lo = 0, hi = N;
        while (lo < hi) { int mid = (lo + hi) >> 1; if (bid[mid] < g) lo = mid + 1; else hi = mid; }
        start[g] = lo;
    }
    __syncthreads();
    if (threadIdx.x == 0) {
        int acc = 0;
        for (int gg = 0; gg < NGRAPHS; ++gg) {
            tpre[gg] = acc;
            acc += (start[gg + 1] - start[gg] + TILE - 1) / TILE;
        }
        tpre[NGRAPHS] = acc;
    }
}

__device__ __forceinline__ void block_tile(const int* __restrict__ tpre, int b,
                                           int& g, int& tile) {
    int lo = 0, hi = NGRAPHS;
    while (hi - lo > 1) {
        int mid = (lo + hi) >> 1;
        if (tpre[mid] <= b) lo = mid; else hi = mid;
    }
    g = lo;
    tile = b - tpre[lo];
}

__global__ __launch_bounds__(256) void stats_kernel(const float* __restrict__ x,
                                                    float* __restrict__ ws) {
    __shared__ float red[256][13];
    const int* start = (const int*)(ws + OFF_START);
    const int* tpre  = (const int*)(ws + OFF_TPRE);
    if ((int)blockIdx.x >= tpre[NGRAPHS]) return;
    int g, tile;
    block_tile(tpre, blockIdx.x, g, tile);
    int r0 = start[g] + tile * TILE;
    int r1 = min(r0 + TILE, start[g + 1]);
    stats_tile(x, g, r0, r1, threadIdx.x & 63, threadIdx.x >> 6, threadIdx.x, red, ws);
}

__global__ __launch_bounds__(256) void norm_kernel(const float* __restrict__ x,
                                                   const float* __restrict__ w,
                                                   const float* __restrict__ bias,
                                                   const float* __restrict__ ws,
                                                   float* __restrict__ out) {
    const int* start = (const int*)(ws + OFF_START);
    const int* tpre  = (const int*)(ws + OFF_TPRE);
    int total = tpre[NGRAPHS];
    int b = total - 1 - (int)blockIdx.x;
    if (b < 0) return;
    int t = threadIdx.x;
    if (t >= 240) return;
    int g, tile;
    block_tile(tpre, b, g, tile);
    int r0 = start[g] + tile * TILE;
    int r1 = min(r0 + TILE, start[g + 1]);
    norm_tile(x, w, bias, ws, out, g, r0, r1, start[g + 1] - start[g],
              t / 120, t % 120);
}

extern "C" void kernel_launch(void* const* d_in, const int* in_sizes, int n_in,
                              void* d_out, int out_size, void* d_ws, size_t ws_size,
                              hipStream_t stream) {
    const float* x   = (const float*)d_in[0];
    const int*   bid = (const int*)d_in[1];
    const float* w   = (const float*)d_in[2];
    const float* b   = (const float*)d_in[3];
    float* ws  = (float*)d_ws;
    float* out = (float*)d_out;
    int N = in_sizes[1];
    int ntiles_ub = (N + TILE - 1) / TILE + NGRAPHS;

    int maxb = 0;
    if (hipOccupancyMaxActiveBlocksPerMultiprocessor(&maxb, fused_kernel, 256, 0) != hipSuccess
        || maxb < 1) maxb = 1;
    int grid = maxb * NCU;
    if (grid > ntiles_ub) grid = ntiles_ub;

    void* args[] = {(void*)&x, (void*)&bid, (void*)&w, (void*)&b,
                    (void*)&ws, (void*)&out, (void*)&N};
    hipError_t e = hipLaunchCooperativeKernel((const void*)fused_kernel, dim3(grid),
                                              dim3(256), args, 0, stream);
    if (e != hipSuccess) {
        // fallback: proven 3-kernel sequence (round 3, 257 us)
        init_kernel<<<89, 256, 0, stream>>>(bid, ws, N);
        stats_kernel<<<ntiles_ub, 256, 0, stream>>>(x, ws);
        norm_kernel<<<ntiles_ub, 256, 0, stream>>>(x, w, b, ws, out);
    }
}

// Round 6
// 266.583 us; speedup vs baseline: 1.6021x; 1.6021x over previous
//
#include <hip/hip_runtime.h>

#define NGRAPHS 64
#define DIM 480            // floats per row
#define NCH 224            // 128 scalar + 64 vec3 + 32 vec5 channels
#define EPS 1e-5f
#define TILE 128           // rows per (graph-aligned) tile

typedef float f32x4 __attribute__((ext_vector_type(4)));

// ws layout (float slots):
// [0, 14336)        sumsq per (g, channel)        64*224
// [14336, 22528)    sum per (g, scalar channel)   64*128
#define OFF_SSQ   0
#define OFF_SUM   14336
#define ZN_BYTES  (22528 * 4)

__device__ __forceinline__ int col2ch(int col) {
    if (col < 128) return col;
    if (col < 320) return 128 + (col - 128) / 3;
    return 192 + (col - 320) / 5;
}

// Per-block: build graph start offsets (binary search over sorted batch_id)
// and tile-prefix table in LDS. ~18 dependent L2 loads of latency, overlapped
// across resident blocks; removes any serial init kernel.
__device__ __forceinline__ void build_tables(const int* __restrict__ bid, int N,
                                             int* s_start, int* s_tpre) {
    int t = threadIdx.x;
    if (t <= NGRAPHS) {
        int g = t, lo = 0, hi = N;          // lower_bound: first i with bid[i] >= g
        while (lo < hi) { int mid = (lo + hi) >> 1; if (bid[mid] < g) lo = mid + 1; else hi = mid; }
        s_start[g] = lo;
    }
    __syncthreads();
    if (t == 0) {
        int acc = 0;
        for (int g = 0; g < NGRAPHS; ++g) {
            s_tpre[g] = acc;
            acc += (s_start[g + 1] - s_start[g] + TILE - 1) / TILE;
        }
        s_tpre[NGRAPHS] = acc;
    }
    __syncthreads();
}

__device__ __forceinline__ void tile_of(const int* s_tpre, int b, int& g, int& tile) {
    int lo = 0, hi = NGRAPHS;               // largest g with tpre[g] <= b
    while (hi - lo > 1) {
        int mid = (lo + hi) >> 1;
        if (s_tpre[mid] <= b) lo = mid; else hi = mid;
    }
    g = lo;
    tile = b - s_tpre[lo];
}

__device__ __forceinline__ void flush_quad(float* __restrict__ SQ, int col0,
                                           float v0, float v1, float v2, float v3) {
    // combine consecutive cols sharing a channel before the atomic
    float v[4] = {v0, v1, v2, v3};
    int ch0 = col2ch(col0), ch1 = col2ch(col0 + 1),
        ch2 = col2ch(col0 + 2), ch3 = col2ch(col0 + 3);
    float acc = v[0]; int cur = ch0;
    if (ch1 == cur) acc += v[1]; else { atomicAdd(&SQ[cur], acc); cur = ch1; acc = v[1]; }
    if (ch2 == cur) acc += v[2]; else { atomicAdd(&SQ[cur], acc); cur = ch2; acc = v[2]; }
    if (ch3 == cur) acc += v[3]; else { atomicAdd(&SQ[cur], acc); cur = ch3; acc = v[3]; }
    atomicAdd(&SQ[cur], acc);
}

// K1: per-(graph,tile) block accumulates sum/sumsq with LDS reduce +
// channel-combined atomic flush. Forward tile order (L3 holds tail at exit).
__global__ __launch_bounds__(256) void stats_kernel(const float* __restrict__ x,
                                                    const int* __restrict__ bid,
                                                    float* __restrict__ ws, int N) {
    __shared__ int s_start[NGRAPHS + 1];
    __shared__ int s_tpre[NGRAPHS + 1];
    __shared__ float red[256][13];          // +1 pad: conflict-free column reads

    build_tables(bid, N, s_start, s_tpre);
    int b = blockIdx.x;
    if (b >= s_tpre[NGRAPHS]) return;
    int g, tile;
    tile_of(s_tpre, b, g, tile);
    int r0 = s_start[g] + tile * TILE;
    int r1 = min(r0 + TILE, s_start[g + 1]);

    const int t  = threadIdx.x;
    const int tx = t & 63;
    const int ty = t >> 6;

    float ssq[8]  = {0, 0, 0, 0, 0, 0, 0, 0};
    float ssum[4] = {0, 0, 0, 0};
    for (int r = r0 + ty; r < r1; r += 4) {
        const float4* rowp = (const float4*)(x + (size_t)r * DIM);
        float4 v0 = rowp[tx];
        ssq[0] += v0.x * v0.x; ssq[1] += v0.y * v0.y;
        ssq[2] += v0.z * v0.z; ssq[3] += v0.w * v0.w;
        if (tx < 32) {                      // cols < 128: scalar channels
            ssum[0] += v0.x; ssum[1] += v0.y; ssum[2] += v0.z; ssum[3] += v0.w;
        }
        if (tx < 56) {
            float4 v1 = rowp[64 + tx];
            ssq[4] += v1.x * v1.x; ssq[5] += v1.y * v1.y;
            ssq[6] += v1.z * v1.z; ssq[7] += v1.w * v1.w;
        }
    }

#pragma unroll
    for (int j = 0; j < 8; ++j) red[t][j] = ssq[j];
#pragma unroll
    for (int j = 0; j < 4; ++j) red[t][8 + j] = ssum[j];
    __syncthreads();
    if (ty == 0) {
        float s[8], sm[4];
#pragma unroll
        for (int j = 0; j < 8; ++j)
            s[j] = red[tx][j] + red[tx + 64][j] + red[tx + 128][j] + red[tx + 192][j];
#pragma unroll
        for (int j = 0; j < 4; ++j)
            sm[j] = red[tx][8 + j] + red[tx + 64][8 + j] + red[tx + 128][8 + j] + red[tx + 192][8 + j];
        float* SQ = ws + OFF_SSQ + (size_t)g * NCH;
        float* SM = ws + OFF_SUM + (size_t)g * 128;
        flush_quad(SQ, 4 * tx, s[0], s[1], s[2], s[3]);
        if (tx < 32) {
#pragma unroll
            for (int j = 0; j < 4; ++j) atomicAdd(&SM[4 * tx + j], sm[j]);
        }
        if (tx < 56) flush_quad(SQ, 256 + 4 * tx, s[4], s[5], s[6], s[7]);
    }
}

// K2: per-(graph,tile) block, REVERSED order (round-5 FETCH data proved this
// makes the re-read of x largely L3-resident). Thread t<240: row_off=t/120,
// c4=t%120 fixed -> A/B computed inline into registers, then pure stream
// out = x*A+B with nontemporal stores.
__global__ __launch_bounds__(256) void norm_kernel(const float* __restrict__ x,
                                                   const int* __restrict__ bid,
                                                   const float* __restrict__ w,
                                                   const float* __restrict__ bias,
                                                   const float* __restrict__ ws,
                                                   float* __restrict__ out, int N) {
    __shared__ int s_start[NGRAPHS + 1];
    __shared__ int s_tpre[NGRAPHS + 1];

    build_tables(bid, N, s_start, s_tpre);
    int total = s_tpre[NGRAPHS];
    int b = total - 1 - (int)blockIdx.x;
    if (b < 0) return;
    int t = threadIdx.x;
    if (t >= 240) return;
    int g, tile;
    tile_of(s_tpre, b, g, tile);
    int r0 = s_start[g] + tile * TILE;
    int r1 = min(r0 + TILE, s_start[g + 1]);

    int row_off = t / 120;                  // 0 or 1
    int c4 = t - row_off * 120;             // fixed col-quad for this thread

    float cnt = (float)max(s_start[g + 1] - s_start[g], 1);
    const float* SQ = ws + OFF_SSQ + (size_t)g * NCH;
    const float* SM = ws + OFF_SUM + (size_t)g * 128;

    float A[4], B[4];
#pragma unroll
    for (int j = 0; j < 4; ++j) {
        int col = 4 * c4 + j;
        int ch = col2ch(col);
        float ssq = SQ[ch];
        if (col < 128) {
            float m   = SM[col] / cnt;
            float var = ssq / cnt - m * m;
            float Av  = rsqrtf(var + EPS) * w[ch];
            A[j] = Av;
            B[j] = bias[col] - m * Av;
        } else {
            float d = (col < 320) ? 3.0f : 5.0f;
            A[j] = rsqrtf(ssq / (d * cnt) + EPS) * w[ch];
            B[j] = 0.0f;
        }
    }

    const float4* xp = (const float4*)(x + (size_t)(r0 + row_off) * DIM) + c4;
    float*        op = out + (size_t)(r0 + row_off) * DIM + 4 * c4;
    const int stride4 = 2 * (DIM / 4);
    const int strideF = 2 * DIM;
    for (int r = r0 + row_off; r < r1; r += 2) {
        float4 xv = *xp;
        f32x4 o;
        o.x = xv.x * A[0] + B[0];
        o.y = xv.y * A[1] + B[1];
        o.z = xv.z * A[2] + B[2];
        o.w = xv.w * A[3] + B[3];
        __builtin_nontemporal_store(o, (f32x4*)op);
        xp += stride4;
        op += strideF;
    }
}

extern "C" void kernel_launch(void* const* d_in, const int* in_sizes, int n_in,
                              void* d_out, int out_size, void* d_ws, size_t ws_size,
                              hipStream_t stream) {
    const float* x   = (const float*)d_in[0];
    const int*   bid = (const int*)d_in[1];
    const float* w   = (const float*)d_in[2];
    const float* b   = (const float*)d_in[3];
    float* ws  = (float*)d_ws;
    float* out = (float*)d_out;
    int N = in_sizes[1];
    int ntiles_ub = (N + TILE - 1) / TILE + NGRAPHS;   // upper bound on tile count

    hipMemsetAsync(ws, 0, ZN_BYTES, stream);           // zero stats accumulators
    stats_kernel<<<ntiles_ub, 256, 0, stream>>>(x, bid, ws, N);
    norm_kernel<<<ntiles_ub, 256, 0, stream>>>(x, bid, w, b, ws, out, N);
}